// Round 4
// baseline (530.682 us; speedup 1.0000x reference)
//
#include <hip/hip_runtime.h>

#define BB 64
#define CC 128
#define CO 128
#define TTOT 256
#define VV 25
#define SS 3
#define RR 16
#define GG 32
#define EPSV 1e-5f

typedef __attribute__((ext_vector_type(8))) __bf16 bf16x8;
typedef __attribute__((ext_vector_type(4))) float f32x4;

static __device__ __forceinline__ ushort f2bf(float f) {
    unsigned u = __float_as_uint(f);
    u = (u + 0x7FFF + ((u >> 16) & 1)) >> 16;   // RNE
    return (ushort)u;
}
static __device__ __forceinline__ float bf2f(ushort h) {
    return __uint_as_float(((unsigned)h) << 16);
}
static __device__ __forceinline__ f32x4 mfma16(bf16x8 a, bf16x8 b, f32x4 c) {
    return __builtin_amdgcn_mfma_f32_16x16x32_bf16(a, b, c, 0, 0, 0);
}

// ---------------- K1: xm = mean over T ----------------
__global__ __launch_bounds__(256) void k_xmean(const float* __restrict__ x,
                                               float* __restrict__ xm) {
    int bc = blockIdx.x;
    const float* xp = x + (size_t)bc * (TTOT * VV);
    int t = threadIdx.x;
    float a[VV];
    const float* row = xp + t * VV;
#pragma unroll
    for (int v = 0; v < VV; ++v) a[v] = row[v];
#pragma unroll
    for (int v = 0; v < VV; ++v) {
#pragma unroll
        for (int off = 32; off > 0; off >>= 1) a[v] += __shfl_down(a[v], off, 64);
    }
    __shared__ float sm[4][VV];
    int wave = t >> 6, lane = t & 63;
    if (lane == 0) {
#pragma unroll
        for (int v = 0; v < VV; ++v) sm[wave][v] = a[v];
    }
    __syncthreads();
    if (t < VV) {
        float s = sm[0][t] + sm[1][t] + sm[2][t] + sm[3][t];
        xm[(size_t)bc * VV + t] = s * (1.0f / TTOT);
    }
}

// ---------------- K1b: pack Wv into bf16 MFMA A-fragment order ----------------
__global__ __launch_bounds__(512) void k_pack_wv(const float* __restrict__ Wv,
                                                 ushort* __restrict__ wvp) {
    int t = blockIdx.x * 512 + threadIdx.x;      // < 6144
    int lane = t & 63;
    int ks = (t >> 6) & 3;
    int mt = (t >> 8) & 1;
    int ob = (t >> 9) & 3;
    int s  = t >> 11;
    int o  = ob * 32 + mt * 16 + (lane & 15);
    int c0 = (ks * 4 + (lane >> 4)) * 8;
    const float* src = Wv + ((size_t)s * CO + o) * CC + c0;
    float4 a = *(const float4*)src;
    float4 b = *(const float4*)(src + 4);
    union { ushort us[8]; int4 v; } u;
    u.us[0] = f2bf(a.x); u.us[1] = f2bf(a.y); u.us[2] = f2bf(a.z); u.us[3] = f2bf(a.w);
    u.us[4] = f2bf(b.x); u.us[5] = f2bf(b.y); u.us[6] = f2bf(b.z); u.us[7] = f2bf(b.w);
    *(int4*)&wvp[(size_t)t * 8] = u.v;
}

// ---------------- K2a: q,k projections ----------------
__global__ __launch_bounds__(512) void k_qk(const float* __restrict__ xm,
    const float* __restrict__ Wq, const float* __restrict__ bq,
    const float* __restrict__ Wk, const float* __restrict__ bk,
    float* __restrict__ qb, float* __restrict__ kbuf) {
    int bs = blockIdx.x;
    int b = bs / SS, s = bs % SS;
    int tid = threadIdx.x;
    __shared__ float sxm[CC * VV];
    for (int i = tid; i < CC * VV; i += 512) sxm[i] = xm[(size_t)b * CC * VV + i];
    __syncthreads();
    if (tid < RR * VV) {
        int r = tid / VV, u = tid % VV;
        const float* wq = Wq + ((size_t)s * RR + r) * CC;
        const float* wk = Wk + ((size_t)s * RR + r) * CC;
        float aq = bq[s * RR + r], ak = bk[s * RR + r];
        for (int c = 0; c < CC; ++c) { float xv = sxm[c * VV + u]; aq += wq[c] * xv; ak += wk[c] * xv; }
        qb[bs * 400 + tid] = aq;
        kbuf[bs * 400 + tid] = ak;
    }
}

// ---------------- K2b: relc -> packed bf16 B-fragment order (8x o-parallel) ----------------
// rp per (b,s,o): [ut(2)][g4(4)][l15(16)][j(8)] = 1024 us; pads written as 0.
__global__ __launch_bounds__(256) void k_relcpack(const float* __restrict__ qb,
    const float* __restrict__ kbuf, const float* __restrict__ Wr,
    const float* __restrict__ br, const float* __restrict__ A,
    const float* __restrict__ alpha, ushort* __restrict__ rp) {
    int blk = blockIdx.x;
    int oc = blk & 7, bs = blk >> 3;
    int s = bs % SS;
    int tid = threadIdx.x;
    __shared__ float sq[RR * VV], sk[RR * VV];
    __shared__ float srel[RR][VV * VV];
    for (int i = tid; i < RR * VV; i += 256) { sq[i] = qb[bs * 400 + i]; sk[i] = kbuf[bs * 400 + i]; }
    __syncthreads();
    for (int i = tid; i < RR * VV * VV; i += 256) {
        int r = i / (VV * VV), uv = i % (VV * VV);
        srel[r][uv] = tanhf(sq[r * VV + uv / VV] - sk[r * VV + uv % VV]);
    }
    __syncthreads();
    float al = alpha[0];
    for (int i = tid; i < 512; i += 256) {
        int ol = i >> 5, u = i & 31;
        int o = oc * 16 + ol;
        ushort* dst = rp + ((size_t)bs * CO + o) * 1024 + (u >> 4) * 512 + (u & 15) * 8;
        if (u < VV) {
            float acc[VV];
            float base = br[s * CO + o];
#pragma unroll
            for (int k = 0; k < VV; ++k) acc[k] = base;
            const float* wr = Wr + ((size_t)s * CO + o) * RR;
#pragma unroll
            for (int r = 0; r < RR; ++r) {
                float w = wr[r];
                const float* sr = &srel[r][u * VV];
#pragma unroll
                for (int k = 0; k < VV; ++k) acc[k] += w * sr[k];
            }
            const float* Ab = A + (size_t)s * VV * VV + u * VV;
#pragma unroll
            for (int kb4 = 0; kb4 < 4; ++kb4) {
                union { ushort us[8]; int4 v; } pk;
#pragma unroll
                for (int j = 0; j < 8; ++j) {
                    int kk = kb4 * 8 + j;
                    pk.us[j] = (kk < VV) ? f2bf(acc[kk] * al + Ab[kk]) : (ushort)0;
                }
                *(int4*)&dst[kb4 * 128] = pk.v;
            }
        } else {
#pragma unroll
            for (int kb4 = 0; kb4 < 4; ++kb4)
                *(int4*)&dst[kb4 * 128] = int4{0, 0, 0, 0};
        }
    }
}

// ---------------- K3: fused MFMA pipeline, dbuf s_v, M=32/wave ----------------
// grid 2048 (b,tch of 8 t), 512 thr (8 waves), 2 blocks/CU (LDS 81664 B).
__global__ __launch_bounds__(512, 4) void k_main(const float* __restrict__ x,
    const ushort* __restrict__ wvp, const float* __restrict__ bv,
    const ushort* __restrict__ rp, ushort* __restrict__ outw,
    float* __restrict__ stats) {
    int bid = blockIdx.x;
    int xcd = bid & 7, g = bid >> 3;
    int b = xcd + 8 * (g >> 5);        // same-b blocks share an XCD -> relc L2 reuse
    int tch = g & 31;
    int tid = threadIdx.x;
    int wvi = tid >> 6;
    int lane = tid & 63;
    int g4 = lane >> 4;
    int l15 = lane & 15;

    __shared__ ushort s_xt[16 * 1600];    // [c8][n(200)][cc(8)], 51200 B
    __shared__ ushort s_v[2 * 32 * 224];  // dbuf: [o(32)][k8<3:64us each | k24 tile:32us], 28672 B
    __shared__ float s_bv[SS * CO];       // 1536 B
    __shared__ float s_gstat[GG * 2];     // 256 B

    if (tid < GG * 2) s_gstat[tid] = 0.f;
    if (tid < SS * CO) s_bv[tid] = bv[tid];
    if (tid < 256) {   // zero the k>=24 pad region [192,224) of every (buf,o)
        int pr = tid >> 2;   // buf*32+o  (buf stride == 32*224)
        *(int4*)&s_v[pr * 224 + 192 + (tid & 3) * 8] = int4{0, 0, 0, 0};
    }

    // ---- stage x tile (bf16) ----
    const float* xb = x + ((size_t)b * CC) * (TTOT * VV) + tch * 200;
    for (int id = wvi; id < 64; id += 8) {
        int c8 = id >> 2, seg = id & 3;
        int n = seg * 64 + lane;
        if (n < 200) {
            float vals[8];
#pragma unroll
            for (int cc = 0; cc < 8; ++cc)
                vals[cc] = xb[(size_t)(c8 * 8 + cc) * (TTOT * VV) + n];
            union { ushort us[8]; int4 v4; } u;
#pragma unroll
            for (int cc = 0; cc < 8; ++cc) u.us[cc] = f2bf(vals[cc]);
            *(int4*)&s_xt[c8 * 1600 + n * 8] = u.v4;
        }
    }

    // ---- per-lane slot constants (hoisted out of all loops) ----
    int n0 = wvi * 16 + l15;
    int n1 = (wvi + 8) * 16 + l15;
    bool v0 = (n0 < 200), v1 = (n1 < 200);
    bool haveS1 = (wvi + 8) < 13;                 // wave-uniform
    int t0 = n0 / 25, k0 = n0 % 25;
    int t1 = n1 / 25, k1 = n1 % 25;
    int vb0 = (k0 < 24) ? ((k0 >> 3) * 64 + t0 * 8 + (k0 & 7)) : (192 + t0 * 4);
    int vb1 = (k1 < 24) ? ((k1 >> 3) * 64 + t1 * 8 + (k1 & 7)) : (192 + t1 * 4);
    int xo0 = (v0 ? n0 : 199) * 8;                // clamped LDS offsets
    int xo1 = (v1 ? n1 : 199) * 8;

    __syncthreads();   // staging + pad-zero + bv ready

    f32x4 acc2[4][2];
#pragma unroll
    for (int oi = 0; oi < 4; ++oi) { acc2[oi][0] = f32x4{0,0,0,0}; acc2[oi][1] = f32x4{0,0,0,0}; }

    bf16x8 afA[2][4], bfB[4][2];

    auto load_af = [&](int st) {
        int ss = st % 3, ob = st / 3;
        const ushort* w0 = wvp + (size_t)((ss * 4 + ob) * 2) * 2048 + lane * 8;
#pragma unroll
        for (int ks = 0; ks < 4; ++ks) {
            afA[0][ks] = *(const bf16x8*)&w0[ks * 512];
            afA[1][ks] = *(const bf16x8*)&w0[2048 + ks * 512];
        }
    };
    auto load_bf = [&](int st) {
        int ss = st % 3, ob = st / 3;
        const ushort* rb = rp + ((size_t)(b * SS + ss) * CO + ob * 32 + wvi * 4) * 1024
                         + g4 * 128 + l15 * 8;
#pragma unroll
        for (int oi = 0; oi < 4; ++oi) {
            bfB[oi][0] = *(const bf16x8*)&rb[oi * 1024];
            bfB[oi][1] = *(const bf16x8*)&rb[oi * 1024 + 512];
        }
    };
    auto do_g1 = [&](int st, ushort* vbuf) {
        int ss = st % 3, ob = st / 3;
        float bvv[2][4];
#pragma unroll
        for (int mt = 0; mt < 2; ++mt)
#pragma unroll
            for (int r = 0; r < 4; ++r)
                bvv[mt][r] = s_bv[ss * CO + ob * 32 + mt * 16 + g4 * 4 + r];
        {
            f32x4 d0 = f32x4{0,0,0,0}, d1 = f32x4{0,0,0,0};
#pragma unroll
            for (int ks = 0; ks < 4; ++ks) {
                bf16x8 bx = *(const bf16x8*)&s_xt[(ks * 4 + g4) * 1600 + xo0];
                d0 = mfma16(afA[0][ks], bx, d0);
                d1 = mfma16(afA[1][ks], bx, d1);
            }
            if (v0) {
#pragma unroll
                for (int r = 0; r < 4; ++r) {
                    vbuf[(g4 * 4 + r) * 224 + vb0]      = f2bf(d0[r] + bvv[0][r]);
                    vbuf[(16 + g4 * 4 + r) * 224 + vb0] = f2bf(d1[r] + bvv[1][r]);
                }
            }
        }
        if (haveS1) {
            f32x4 d0 = f32x4{0,0,0,0}, d1 = f32x4{0,0,0,0};
#pragma unroll
            for (int ks = 0; ks < 4; ++ks) {
                bf16x8 bx = *(const bf16x8*)&s_xt[(ks * 4 + g4) * 1600 + xo1];
                d0 = mfma16(afA[0][ks], bx, d0);
                d1 = mfma16(afA[1][ks], bx, d1);
            }
            if (v1) {
#pragma unroll
                for (int r = 0; r < 4; ++r) {
                    vbuf[(g4 * 4 + r) * 224 + vb1]      = f2bf(d0[r] + bvv[0][r]);
                    vbuf[(16 + g4 * 4 + r) * 224 + vb1] = f2bf(d1[r] + bvv[1][r]);
                }
            }
        }
    };
    auto do_g2 = [&](const ushort* vbuf) {
#pragma unroll
        for (int oi = 0; oi < 4; ++oi) {
            int ol = wvi * 4 + oi;
            bf16x8 av;
            if (g4 < 3) {
                av = *(const bf16x8*)&vbuf[ol * 224 + g4 * 64 + (l15 & 7) * 8];
            } else {
                union { ushort us[8]; bf16x8 v; } u;
                *(ushort4*)&u.us[0] = *(const ushort4*)&vbuf[ol * 224 + 192 + (l15 & 7) * 4];
                u.us[4] = 0; u.us[5] = 0; u.us[6] = 0; u.us[7] = 0;
                av = u.v;
            }
            acc2[oi][0] = mfma16(av, bfB[oi][0], acc2[oi][0]);
            acc2[oi][1] = mfma16(av, bfB[oi][1], acc2[oi][1]);
        }
    };
    auto do_epi = [&](int ob) {
#pragma unroll
        for (int oi = 0; oi < 4; ++oi) {
            int o = ob * 32 + wvi * 4 + oi;
            float ps = 0.f, pq = 0.f;
            if (g4 < 2) {
#pragma unroll
                for (int ut = 0; ut < 2; ++ut) {
                    int u = ut * 16 + l15;
                    if (u < VV) {
#pragma unroll
                        for (int r = 0; r < 4; ++r) {
                            float val = acc2[oi][ut][r];
                            int t = g4 * 4 + r;
                            outw[(((size_t)b * CO + o) * TTOT + tch * 8 + t) * VV + u] = f2bf(val);
                            ps += val; pq += val * val;
                        }
                    }
                }
            }
#pragma unroll
            for (int off = 32; off > 0; off >>= 1) {
                ps += __shfl_down(ps, off, 64);
                pq += __shfl_down(pq, off, 64);
            }
            if (lane == 0) {
                atomicAdd(&s_gstat[(o >> 2) * 2], ps);
                atomicAdd(&s_gstat[(o >> 2) * 2 + 1], pq);
            }
            acc2[oi][0] = f32x4{0,0,0,0};
            acc2[oi][1] = f32x4{0,0,0,0};
        }
    };

    load_af(0);
    do_g1(0, s_v);                       // buf0
    for (int st = 0; st < 12; ++st) {
        ushort* rbuf = s_v + (st & 1) * (32 * 224);
        ushort* wbuf = s_v + ((st & 1) ^ 1) * (32 * 224);
        __syncthreads();                 // G1(st) writes + prev G2 reads complete
        load_bf(st);
        if (st < 11) {
            load_af(st + 1);
            do_g1(st + 1, wbuf);         // overlaps with G2(st)
        }
        do_g2(rbuf);
        if (st % 3 == 2) do_epi(st / 3);
    }
    __syncthreads();
    if (tid < GG * 2) atomicAdd(&stats[b * (GG * 2) + tid], s_gstat[tid]);
}

// ---------------- K4: GroupNorm apply + residual + ReLU ----------------
__global__ __launch_bounds__(256) void k_final(float* __restrict__ out,
    const ushort* __restrict__ outw, const float* __restrict__ x,
    const float* __restrict__ stats,
    const float* __restrict__ gw, const float* __restrict__ gb) {
    size_t i = ((size_t)blockIdx.x * 256 + threadIdx.x) * 4;
    int o = (int)((i / (TTOT * VV)) % CO);
    int b = (int)(i / ((size_t)CO * TTOT * VV));
    int gg = o >> 2;
    float s0 = stats[b * (GG * 2) + gg * 2];
    float s1 = stats[b * (GG * 2) + gg * 2 + 1];
    const float inv = 1.0f / (4 * TTOT * VV);
    float mu = s0 * inv;
    float var = s1 * inv - mu * mu;
    float rs = rsqrtf(var + EPSV) * gw[o];
    float sh = gb[o] - mu * rs;

    ushort4 rw = *(const ushort4*)(outw + i);
    float4 xr = *(const float4*)(x + i);
    float4 res;
    res.x = fmaxf(bf2f(rw.x) * rs + sh + xr.x, 0.f);
    res.y = fmaxf(bf2f(rw.y) * rs + sh + xr.y, 0.f);
    res.z = fmaxf(bf2f(rw.z) * rs + sh + xr.z, 0.f);
    res.w = fmaxf(bf2f(rw.w) * rs + sh + xr.w, 0.f);
    *(float4*)(out + i) = res;
}

extern "C" void kernel_launch(void* const* d_in, const int* in_sizes, int n_in,
                              void* d_out, int out_size, void* d_ws, size_t ws_size,
                              hipStream_t stream) {
    const float* x     = (const float*)d_in[0];
    const float* Wq    = (const float*)d_in[1];
    const float* bq    = (const float*)d_in[2];
    const float* Wk    = (const float*)d_in[3];
    const float* bk    = (const float*)d_in[4];
    const float* Wv    = (const float*)d_in[5];
    const float* bv    = (const float*)d_in[6];
    const float* Wr    = (const float*)d_in[7];
    const float* br    = (const float*)d_in[8];
    const float* A     = (const float*)d_in[9];
    const float* alpha = (const float*)d_in[10];
    const float* gw    = (const float*)d_in[11];
    const float* gb    = (const float*)d_in[12];
    float* out = (float*)d_out;

    float*  xm    = (float*)d_ws;                               // 204800 f
    float*  stats = xm + (size_t)BB * CC * VV;                  // 4096 f
    ushort* wvp   = (ushort*)(stats + (size_t)BB * GG * 2);     // 49152 us
    ushort* rp    = wvp + 49152;                                // 25165824 us
    ushort* outw  = rp + (size_t)BB * SS * CO * 1024;           // 52428800 us
    // q/k buffers live in the (not-yet-written) outw region: consumed before k_main
    float*  qb    = (float*)outw;                               // 76800 f
    float*  kbuf  = qb + (size_t)BB * SS * RR * VV;             // 76800 f

    hipMemsetAsync(stats, 0, (size_t)BB * GG * 2 * sizeof(float), stream);
    k_xmean<<<BB * CC, 256, 0, stream>>>(x, xm);
    k_pack_wv<<<12, 512, 0, stream>>>(Wv, wvp);
    k_qk<<<BB * SS, 512, 0, stream>>>(xm, Wq, bq, Wk, bk, qb, kbuf);
    k_relcpack<<<BB * SS * 8, 256, 0, stream>>>(qb, kbuf, Wr, br, A, alpha, rp);
    k_main<<<2048, 512, 0, stream>>>(x, wvp, bv, rp, outw, stats);
    k_final<<<(BB * CO * TTOT * VV) / (256 * 4), 256, 0, stream>>>(out, outw, x, stats, gw, gb);
}

// Round 5
// 465.523 us; speedup vs baseline: 1.1400x; 1.1400x over previous
//
#include <hip/hip_runtime.h>

#define BB 64
#define CC 128
#define CO 128
#define TTOT 256
#define VV 25
#define SS 3
#define RR 16
#define GG 32
#define EPSV 1e-5f

typedef __attribute__((ext_vector_type(8))) __bf16 bf16x8;
typedef __attribute__((ext_vector_type(4))) float f32x4;

static __device__ __forceinline__ ushort f2bf(float f) {      // RNE, 3 ops (precompute)
    unsigned u = __float_as_uint(f);
    u = (u + 0x7FFF + ((u >> 16) & 1)) >> 16;
    return (ushort)u;
}
static __device__ __forceinline__ ushort f2bf_fast(float f) { // round-half-up, 2 ops (hot path)
    return (ushort)((__float_as_uint(f) + 0x8000u) >> 16);
}
static __device__ __forceinline__ float bf2f(ushort h) {
    return __uint_as_float(((unsigned)h) << 16);
}
static __device__ __forceinline__ f32x4 mfma16(bf16x8 a, bf16x8 b, f32x4 c) {
    return __builtin_amdgcn_mfma_f32_16x16x32_bf16(a, b, c, 0, 0, 0);
}

// ---------------- K1: xm = mean over T (+ optional x -> bf16 transcode) ----------------
template<bool XB>
__global__ __launch_bounds__(256) void k_xmean(const float* __restrict__ x,
                                               float* __restrict__ xm,
                                               ushort* __restrict__ xb16) {
    int bc = blockIdx.x;
    const float* xp = x + (size_t)bc * (TTOT * VV);
    int t = threadIdx.x;
    float a[VV];
    const float* row = xp + t * VV;
#pragma unroll
    for (int v = 0; v < VV; ++v) a[v] = row[v];
    if (XB) {
        ushort* orow = xb16 + (size_t)bc * (TTOT * VV) + t * VV;
#pragma unroll
        for (int v = 0; v < VV; ++v) orow[v] = f2bf(a[v]);
    }
#pragma unroll
    for (int v = 0; v < VV; ++v) {
#pragma unroll
        for (int off = 32; off > 0; off >>= 1) a[v] += __shfl_down(a[v], off, 64);
    }
    __shared__ float sm[4][VV];
    int wave = t >> 6, lane = t & 63;
    if (lane == 0) {
#pragma unroll
        for (int v = 0; v < VV; ++v) sm[wave][v] = a[v];
    }
    __syncthreads();
    if (t < VV) {
        float s = sm[0][t] + sm[1][t] + sm[2][t] + sm[3][t];
        xm[(size_t)bc * VV + t] = s * (1.0f / TTOT);
    }
}

// ---------------- K1b: pack Wv into bf16 MFMA A-fragment order ----------------
__global__ __launch_bounds__(512) void k_pack_wv(const float* __restrict__ Wv,
                                                 ushort* __restrict__ wvp) {
    int t = blockIdx.x * 512 + threadIdx.x;      // < 6144
    int lane = t & 63;
    int ks = (t >> 6) & 3;
    int mt = (t >> 8) & 1;
    int ob = (t >> 9) & 3;
    int s  = t >> 11;
    int o  = ob * 32 + mt * 16 + (lane & 15);
    int c0 = (ks * 4 + (lane >> 4)) * 8;
    const float* src = Wv + ((size_t)s * CO + o) * CC + c0;
    float4 a = *(const float4*)src;
    float4 b = *(const float4*)(src + 4);
    union { ushort us[8]; int4 v; } u;
    u.us[0] = f2bf(a.x); u.us[1] = f2bf(a.y); u.us[2] = f2bf(a.z); u.us[3] = f2bf(a.w);
    u.us[4] = f2bf(b.x); u.us[5] = f2bf(b.y); u.us[6] = f2bf(b.z); u.us[7] = f2bf(b.w);
    *(int4*)&wvp[(size_t)t * 8] = u.v;
}

// ---------------- K2a: q,k projections ----------------
__global__ __launch_bounds__(512) void k_qk(const float* __restrict__ xm,
    const float* __restrict__ Wq, const float* __restrict__ bq,
    const float* __restrict__ Wk, const float* __restrict__ bk,
    float* __restrict__ qb, float* __restrict__ kbuf) {
    int bs = blockIdx.x;
    int b = bs / SS, s = bs % SS;
    int tid = threadIdx.x;
    __shared__ float sxm[CC * VV];
    for (int i = tid; i < CC * VV; i += 512) sxm[i] = xm[(size_t)b * CC * VV + i];
    __syncthreads();
    if (tid < RR * VV) {
        int r = tid / VV, u = tid % VV;
        const float* wq = Wq + ((size_t)s * RR + r) * CC;
        const float* wk = Wk + ((size_t)s * RR + r) * CC;
        float aq = bq[s * RR + r], ak = bk[s * RR + r];
        for (int c = 0; c < CC; ++c) { float xv = sxm[c * VV + u]; aq += wq[c] * xv; ak += wk[c] * xv; }
        qb[bs * 400 + tid] = aq;
        kbuf[bs * 400 + tid] = ak;
    }
}

// ---------------- K2b: relc -> packed bf16 B-fragments, LDS-staged coalesced write ----------------
__global__ __launch_bounds__(256) void k_relcpack(const float* __restrict__ qb,
    const float* __restrict__ kbuf, const float* __restrict__ Wr,
    const float* __restrict__ br, const float* __restrict__ A,
    const float* __restrict__ alpha, ushort* __restrict__ rp) {
    int blk = blockIdx.x;
    int oc = blk & 7, bs = blk >> 3;
    int s = bs % SS;
    int tid = threadIdx.x;
    __shared__ float sq[RR * VV], sk[RR * VV];
    __shared__ float srel[RR][VV * VV];
    __shared__ ushort spack[16 * 1024];
    for (int i = tid; i < RR * VV; i += 256) { sq[i] = qb[bs * 400 + i]; sk[i] = kbuf[bs * 400 + i]; }
    __syncthreads();
    for (int i = tid; i < RR * VV * VV; i += 256) {
        int r = i / (VV * VV), uv = i % (VV * VV);
        srel[r][uv] = tanhf(sq[r * VV + uv / VV] - sk[r * VV + uv % VV]);
    }
    __syncthreads();
    float al = alpha[0];
    for (int i = tid; i < 512; i += 256) {
        int ol = i >> 5, u = i & 31;
        int o = oc * 16 + ol;
        ushort* dst = &spack[ol * 1024 + (u >> 4) * 512 + (u & 15) * 8];
        if (u < VV) {
            float acc[VV];
            float base = br[s * CO + o];
#pragma unroll
            for (int k = 0; k < VV; ++k) acc[k] = base;
            const float* wr = Wr + ((size_t)s * CO + o) * RR;
#pragma unroll
            for (int r = 0; r < RR; ++r) {
                float w = wr[r];
                const float* sr = &srel[r][u * VV];
#pragma unroll
                for (int k = 0; k < VV; ++k) acc[k] += w * sr[k];
            }
            const float* Ab = A + (size_t)s * VV * VV + u * VV;
#pragma unroll
            for (int kb4 = 0; kb4 < 4; ++kb4) {
                union { ushort us[8]; int4 v; } pk;
#pragma unroll
                for (int j = 0; j < 8; ++j) {
                    int kk = kb4 * 8 + j;
                    pk.us[j] = (kk < VV) ? f2bf(acc[kk] * al + Ab[kk]) : (ushort)0;
                }
                *(int4*)&dst[kb4 * 128] = pk.v;
            }
        } else {
#pragma unroll
            for (int kb4 = 0; kb4 < 4; ++kb4)
                *(int4*)&dst[kb4 * 128] = int4{0, 0, 0, 0};
        }
    }
    __syncthreads();
    int4* dstg = (int4*)(rp + ((size_t)bs * CO + oc * 16) * 1024);
    const int4* srcs = (const int4*)spack;
    for (int i = tid; i < 2048; i += 256) dstg[i] = srcs[i];
}

// ---------------- K3: fused MFMA pipeline (R3 schedule + prefetch + hoists + swizzle) ----------------
template<bool XB>
__global__ __launch_bounds__(512, 4) void k_main(const void* __restrict__ xsrc,
    const ushort* __restrict__ wvp, const float* __restrict__ bv,
    const ushort* __restrict__ rp, ushort* __restrict__ outw,
    float* __restrict__ stats) {
    int bid = blockIdx.x;
    int b = (bid & 7) + 8 * (bid >> 8);     // same-b blocks share an XCD
    int tch = (bid >> 3) & 31;
    int tid = threadIdx.x;
    int wvi = tid >> 6;
    int lane = tid & 63;
    int g4 = lane >> 4, l15 = lane & 15;
    int mt = wvi & 1, sb = wvi >> 1;

    __shared__ ushort s_xt[16 * 1600];   // [c8][n(200)][cc(8)] bf16, 51.2 KB
    __shared__ ushort s_v[32 * 256];     // [o][k8][t][kk] bf16 (XOR-swizzled), 16 KB
    __shared__ float s_bv[SS * CO];

    if (tid < SS * CO) s_bv[tid] = bv[tid];
    if (tid < 256) {   // zero k>=24 pad region (closed under the XOR swizzle)
        int o = tid >> 3, t = tid & 7;
        *(int4*)&s_v[o * 256 + 192 + t * 8] = int4{0, 0, 0, 0};
    }

    // per-thread fragment bases
    const ushort* rpb = rp + (size_t)b * (SS * CO * 1024) + wvi * 4096 + g4 * 128 + l15 * 8;
    const ushort* wpb = wvp + mt * 2048 + lane * 8;

    // stage-0 fragment loads (latency covered by x staging)
    bf16x8 af[4], bf[4][2];
#pragma unroll
    for (int ks = 0; ks < 4; ++ks) af[ks] = *(const bf16x8*)&wpb[ks * 512];
#pragma unroll
    for (int oi = 0; oi < 4; ++oi) {
        bf[oi][0] = *(const bf16x8*)&rpb[oi * 1024];
        bf[oi][1] = *(const bf16x8*)&rpb[oi * 1024 + 512];
    }

    // ---- stage x tile ----
    if (XB) {
        const ushort* xb = (const ushort*)xsrc + (size_t)b * (CC * TTOT * VV) + tch * 200;
        for (int id = wvi; id < 64; id += 8) {
            int c8 = id >> 2, seg = id & 3;
            int n = seg * 64 + lane;
            if (n < 200) {
                union { ushort us[8]; int4 v4; } u;
#pragma unroll
                for (int cc = 0; cc < 8; ++cc)
                    u.us[cc] = xb[(size_t)(c8 * 8 + cc) * (TTOT * VV) + n];
                *(int4*)&s_xt[c8 * 1600 + n * 8] = u.v4;
            }
        }
    } else {
        const float* xb = (const float*)xsrc + (size_t)b * (CC * TTOT * VV) + tch * 200;
        for (int id = wvi; id < 64; id += 8) {
            int c8 = id >> 2, seg = id & 3;
            int n = seg * 64 + lane;
            if (n < 200) {
                union { ushort us[8]; int4 v4; } u;
#pragma unroll
                for (int cc = 0; cc < 8; ++cc)
                    u.us[cc] = f2bf(xb[(size_t)(c8 * 8 + cc) * (TTOT * VV) + n]);
                *(int4*)&s_xt[c8 * 1600 + n * 8] = u.v4;
            }
        }
    }

    // ---- hoisted per-slot constants ----
    int xo[4], vbx[4];
    bool sv[4];
#pragma unroll
    for (int i = 0; i < 4; ++i) {
        int nt = sb + 4 * i;               // slots nt, nt+4, nt+8, nt+12
        int n = nt * 16 + l15;
        bool valid = (n < 200);
        sv[i] = valid;
        int nn = valid ? n : 0;
        xo[i] = nn * 8;
        int t = nn / 25, k = nn % 25;
        vbx[i] = ((k >> 3) * 64 + t * 8 + (k & 7)) ^ (g4 << 3);   // write swizzle: mask=(o>>2)&3=g4
    }
    int avoff[4];
#pragma unroll
    for (int oi = 0; oi < 4; ++oi)          // read swizzle: mask=(ol>>2)&3=wvi&3
        avoff[oi] = (wvi * 4 + oi) * 256 + g4 * 64 + (((l15 & 7) * 8) ^ ((wvi & 3) << 3));

    f32x4 acc2[4][2];
#pragma unroll
    for (int oi = 0; oi < 4; ++oi) { acc2[oi][0] = f32x4{0,0,0,0}; acc2[oi][1] = f32x4{0,0,0,0}; }
    float psum[4], pqsum[4];

#pragma unroll
    for (int st = 0; st < 12; ++st) {
        const int ob = st / 3, ss = st % 3;
        __syncthreads();                     // A: staging done / prev GEMM2 s_v reads done
        float4 bvv = *(const float4*)&s_bv[ss * CO + ob * 32 + mt * 16 + g4 * 4];

        // ---- GEMM1: v = Wv_s @ xt -> s_v (swizzled) ----
#pragma unroll
        for (int i = 0; i < 4; ++i) {
            f32x4 d = f32x4{0,0,0,0};
#pragma unroll
            for (int ks = 0; ks < 4; ++ks)
                d = mfma16(af[ks], *(const bf16x8*)&s_xt[(ks * 4 + g4) * 1600 + xo[i]], d);
            if (sv[i]) {
                int rowb = mt * 16 + g4 * 4;
                s_v[(rowb    ) * 256 + vbx[i]] = f2bf_fast(d[0] + bvv.x);
                s_v[(rowb + 1) * 256 + vbx[i]] = f2bf_fast(d[1] + bvv.y);
                s_v[(rowb + 2) * 256 + vbx[i]] = f2bf_fast(d[2] + bvv.z);
                s_v[(rowb + 3) * 256 + vbx[i]] = f2bf_fast(d[3] + bvv.w);
            }
        }
        // prefetch next-stage A frags (af dead; cover = barrier B + GEMM2)
        if (st < 11) {
            const ushort* w1 = wpb + (((st + 1) % 3) * 4 + (st + 1) / 3) * 4096;
#pragma unroll
            for (int ks = 0; ks < 4; ++ks) af[ks] = *(const bf16x8*)&w1[ks * 512];
        }
        __syncthreads();                     // B: s_v ready

        // ---- GEMM2: acc2 += v · relc^T ----
#pragma unroll
        for (int oi = 0; oi < 4; ++oi) {
            bf16x8 av = *(const bf16x8*)&s_v[avoff[oi]];
            acc2[oi][0] = mfma16(av, bf[oi][0], acc2[oi][0]);
            acc2[oi][1] = mfma16(av, bf[oi][1], acc2[oi][1]);
        }
        // prefetch next-stage B frags (bf dead)
        if (st < 11) {
            const ushort* r1 = rpb + ((st + 1) % 3) * 131072 + ((st + 1) / 3) * 32768;
#pragma unroll
            for (int oi = 0; oi < 4; ++oi) {
                bf[oi][0] = *(const bf16x8*)&r1[oi * 1024];
                bf[oi][1] = *(const bf16x8*)&r1[oi * 1024 + 512];
            }
        }

        // ---- epilogue after each ob completes ----
        if (ss == 2) {
            float ps = 0.f, pq = 0.f;
#pragma unroll
            for (int oi = 0; oi < 4; ++oi) {
                int o = ob * 32 + wvi * 4 + oi;
                if (g4 < 2) {
                    size_t obase = (((size_t)b * CO + o) * TTOT + tch * 8 + g4 * 4) * VV;
#pragma unroll
                    for (int ut = 0; ut < 2; ++ut) {
                        int u = ut * 16 + l15;
                        if (u < VV) {
#pragma unroll
                            for (int r = 0; r < 4; ++r) {
                                float val = acc2[oi][ut][r];
                                outw[obase + (size_t)r * VV + u] = f2bf_fast(val);
                                ps += val; pq += val * val;
                            }
                        }
                    }
                }
                acc2[oi][0] = f32x4{0,0,0,0};
                acc2[oi][1] = f32x4{0,0,0,0};
            }
            psum[ob] = ps; pqsum[ob] = pq;
        }
    }

    // ---- stats: group = ob*8 + wvi (unique per wave), 5-level reduce over lanes 0-31 ----
#pragma unroll
    for (int ob = 0; ob < 4; ++ob) {
        float ps = psum[ob], pq = pqsum[ob];
#pragma unroll
        for (int off = 16; off > 0; off >>= 1) {
            ps += __shfl_down(ps, off, 64);
            pq += __shfl_down(pq, off, 64);
        }
        if (lane == 0) {
            atomicAdd(&stats[b * (GG * 2) + (ob * 8 + wvi) * 2], ps);
            atomicAdd(&stats[b * (GG * 2) + (ob * 8 + wvi) * 2 + 1], pq);
        }
    }
}

// ---------------- K4: GroupNorm apply + residual + ReLU ----------------
template<bool XB>
__global__ __launch_bounds__(256) void k_final(float* __restrict__ out,
    const ushort* __restrict__ outw, const void* __restrict__ xsrc,
    const float* __restrict__ stats,
    const float* __restrict__ gw, const float* __restrict__ gb) {
    size_t i = ((size_t)blockIdx.x * 256 + threadIdx.x) * 4;
    int o = (int)((i / (TTOT * VV)) % CO);
    int b = (int)(i / ((size_t)CO * TTOT * VV));
    int gg = o >> 2;
    float s0 = stats[b * (GG * 2) + gg * 2];
    float s1 = stats[b * (GG * 2) + gg * 2 + 1];
    const float inv = 1.0f / (4 * TTOT * VV);
    float mu = s0 * inv;
    float var = s1 * inv - mu * mu;
    float rs = rsqrtf(var + EPSV) * gw[o];
    float sh = gb[o] - mu * rs;

    ushort4 rw = *(const ushort4*)(outw + i);
    float4 xr;
    if (XB) {
        ushort4 xw = *(const ushort4*)((const ushort*)xsrc + i);
        xr.x = bf2f(xw.x); xr.y = bf2f(xw.y); xr.z = bf2f(xw.z); xr.w = bf2f(xw.w);
    } else {
        xr = *(const float4*)((const float*)xsrc + i);
    }
    float4 res;
    res.x = fmaxf(bf2f(rw.x) * rs + sh + xr.x, 0.f);
    res.y = fmaxf(bf2f(rw.y) * rs + sh + xr.y, 0.f);
    res.z = fmaxf(bf2f(rw.z) * rs + sh + xr.z, 0.f);
    res.w = fmaxf(bf2f(rw.w) * rs + sh + xr.w, 0.f);
    *(float4*)(out + i) = res;
}

extern "C" void kernel_launch(void* const* d_in, const int* in_sizes, int n_in,
                              void* d_out, int out_size, void* d_ws, size_t ws_size,
                              hipStream_t stream) {
    const float* x     = (const float*)d_in[0];
    const float* Wq    = (const float*)d_in[1];
    const float* bq    = (const float*)d_in[2];
    const float* Wk    = (const float*)d_in[3];
    const float* bk    = (const float*)d_in[4];
    const float* Wv    = (const float*)d_in[5];
    const float* bv    = (const float*)d_in[6];
    const float* Wr    = (const float*)d_in[7];
    const float* br    = (const float*)d_in[8];
    const float* A     = (const float*)d_in[9];
    const float* alpha = (const float*)d_in[10];
    const float* gw    = (const float*)d_in[11];
    const float* gb    = (const float*)d_in[12];
    float* out = (float*)d_out;

    float*  xm    = (float*)d_ws;                               // 204800 f
    float*  stats = xm + (size_t)BB * CC * VV;                  // 4096 f
    ushort* wvp   = (ushort*)(stats + (size_t)BB * GG * 2);     // 49152 us
    ushort* rp    = wvp + 49152;                                // 25165824 us
    ushort* outw  = rp + (size_t)BB * SS * CO * 1024;           // 52428800 us
    ushort* xb16  = outw + (size_t)BB * CO * TTOT * VV;         // 52428800 us (optional)
    float*  qb    = (float*)outw;                               // overlay: consumed pre-k_main
    float*  kbuf  = qb + (size_t)BB * SS * RR * VV;

    size_t need_fixed = 819200 + 16384 + 98304 + 50331648 + 104857600;
    size_t need_xb = need_fixed + 104857600;
    bool xbp = (ws_size >= need_xb);

    hipMemsetAsync(stats, 0, (size_t)BB * GG * 2 * sizeof(float), stream);
    if (xbp) k_xmean<true><<<BB * CC, 256, 0, stream>>>(x, xm, xb16);
    else     k_xmean<false><<<BB * CC, 256, 0, stream>>>(x, xm, xb16);
    k_pack_wv<<<12, 512, 0, stream>>>(Wv, wvp);
    k_qk<<<BB * SS, 512, 0, stream>>>(xm, Wq, bq, Wk, bk, qb, kbuf);
    k_relcpack<<<BB * SS * 8, 256, 0, stream>>>(qb, kbuf, Wr, br, A, alpha, rp);
    int nfin = (BB * CO * TTOT * VV) / (256 * 4);
    if (xbp) {
        k_main<true><<<2048, 512, 0, stream>>>(xb16, wvp, bv, rp, outw, stats);
        k_final<true><<<nfin, 256, 0, stream>>>(out, outw, xb16, stats, gw, gb);
    } else {
        k_main<false><<<2048, 512, 0, stream>>>(x, wvp, bv, rp, outw, stats);
        k_final<false><<<nfin, 256, 0, stream>>>(out, outw, x, stats, gw, gb);
    }
}